// Round 7
// baseline (231.371 us; speedup 1.0000x reference)
//
#include <hip/hip_runtime.h>
#include <math.h>

#define T_TOK 4096
#define D_DIM 2048
#define E_EXP 8
#define NBLK 256
#define BTHR 1024
#define ROWS_PER_BLK ((E_EXP * T_TOK) / NBLK)   // 128
#define TOK_PER_BLK (T_TOK / NBLK)              // 16

typedef float f32x4 __attribute__((ext_vector_type(4)));

struct TokRec { int e0, e1; float g0, g1; };

union SmemU {
    float wgt[E_EXP * D_DIM];                   // 64 KB — phase 0/1
    struct {                                    // 60 KB — phase 2/3
        uint4 sb[256];                          // 4 KB
        int offlds[256 * 8];                    // 8 KB
        unsigned short src[2 * T_TOK];          // 16 KB
        float gate[2 * T_TOK];                  // 32 KB
        int loads[E_EXP];
        int base[E_EXP];
    } s;
};

__global__ __launch_bounds__(BTHR) void fused_kernel(const float* __restrict__ x,
                                                     const float* __restrict__ Wg,
                                                     TokRec* __restrict__ recs,
                                                     unsigned* __restrict__ bar,
                                                     float* __restrict__ out_data,
                                                     float* __restrict__ out_tags,
                                                     float* __restrict__ out_loads) {
    __shared__ SmemU u;
    const int tid = threadIdx.x;
    const int b = blockIdx.x;

    // ---- Phase 0: stage Wg[d][e] -> LDS transposed wgt[e][d] ----
#pragma unroll
    for (int it = 0; it < (E_EXP * D_DIM) / (BTHR * 4); ++it) {
        const int flat = (it * BTHR + tid) * 4;
        const f32x4 w = *reinterpret_cast<const f32x4*>(Wg + flat);
        const int d = flat >> 3;
        const int e0 = flat & 7;            // 0 or 4
        u.wgt[(e0 + 0) * D_DIM + d] = w.x;
        u.wgt[(e0 + 1) * D_DIM + d] = w.y;
        u.wgt[(e0 + 2) * D_DIM + d] = w.z;
        u.wgt[(e0 + 3) * D_DIM + d] = w.w;
    }
    __syncthreads();

    // ---- Phase 1: gating, ONE token per wave (16 waves = 16 tokens/block) ----
    // Per-token arithmetic identical to R5 (bit-identical routing decisions).
    {
        const int wave = tid >> 6;
        const int lane = tid & 63;
        const int t = b * TOK_PER_BLK + wave;
        const float* xr = x + (size_t)t * D_DIM;
        double acc[E_EXP];
#pragma unroll
        for (int e = 0; e < E_EXP; ++e) acc[e] = 0.0;
#pragma unroll
        for (int i = 0; i < D_DIM / 256; ++i) {
            const int d = i * 256 + lane * 4;
            const f32x4 xv = *reinterpret_cast<const f32x4*>(xr + d);
#pragma unroll
            for (int e = 0; e < E_EXP; ++e) {
                const f32x4 w = *reinterpret_cast<const f32x4*>(&u.wgt[e * D_DIM + d]);
                acc[e] += (double)xv.x * (double)w.x + (double)xv.y * (double)w.y
                        + (double)xv.z * (double)w.z + (double)xv.w * (double)w.w;
            }
        }
#pragma unroll
        for (int e = 0; e < E_EXP; ++e) {
            double v = acc[e];
#pragma unroll
            for (int off = 32; off > 0; off >>= 1) v += __shfl_xor(v, off, 64);
            acc[e] = v;
        }
        if (lane == 0) {
            double m = acc[0];
#pragma unroll
            for (int e = 1; e < E_EXP; ++e) m = (acc[e] > m) ? acc[e] : m;
            double Z = 0.0;
#pragma unroll
            for (int e = 0; e < E_EXP; ++e) Z += exp(acc[e] - m);
            int e0 = 0;
#pragma unroll
            for (int e = 1; e < E_EXP; ++e) if (acc[e] > acc[e0]) e0 = e;
            int e1 = (e0 == 0) ? 1 : 0;
#pragma unroll
            for (int e = 0; e < E_EXP; ++e) if (e != e0 && acc[e] > acc[e1]) e1 = e;
            TokRec r;
            r.e0 = e0; r.e1 = e1;
            r.g0 = (float)(exp(acc[e0] - m) / Z);
            r.g1 = (float)(exp(acc[e1] - m) / Z);
            recs[t] = r;
        }
    }

    // ---- Grid barrier (protocol identical to R6, which validated) ----
    __threadfence();
    __syncthreads();
    if (tid == 0) {
        atomicAdd(bar, 1u);
        while (__hip_atomic_load(bar, __ATOMIC_ACQUIRE, __HIP_MEMORY_SCOPE_AGENT) < NBLK) {}
    }
    __syncthreads();
    __threadfence();

    // ---- Phase 2: redundant per-block scan on first 256 threads ----
    {
        TokRec rl[16];
        uint4 v, own;
        if (tid < 256) {
            const int t0 = tid * 16;
            unsigned long long c = 0ULL;
            for (int k = 0; k < 16; ++k) {
                rl[k] = recs[t0 + k];
                c += 1ULL << (rl[k].e0 * 8);
                c += 1ULL << (rl[k].e1 * 8);
            }
            v.x = (unsigned)((c       ) & 0xFF) | ((unsigned)((c >>  8) & 0xFF) << 16);
            v.y = (unsigned)((c >> 16 ) & 0xFF) | ((unsigned)((c >> 24) & 0xFF) << 16);
            v.z = (unsigned)((c >> 32 ) & 0xFF) | ((unsigned)((c >> 40) & 0xFF) << 16);
            v.w = (unsigned)((c >> 48 ) & 0xFF) | ((unsigned)((c >> 56) & 0xFF) << 16);
            own = v;
            u.s.sb[tid] = v;
        }
        for (int d = 1; d < 256; d <<= 1) {
            __syncthreads();
            uint4 o = make_uint4(0u, 0u, 0u, 0u);
            if (tid >= d && tid < 256) o = u.s.sb[tid - d];
            __syncthreads();
            if (tid < 256) {
                v.x += o.x; v.y += o.y; v.z += o.z; v.w += o.w;
                u.s.sb[tid] = v;
            }
        }
        __syncthreads();
        if (tid == 0) {
            const uint4 tot = u.s.sb[255];
            int ld[8];
            ld[0] = (int)(tot.x & 0xFFFF); ld[1] = (int)(tot.x >> 16);
            ld[2] = (int)(tot.y & 0xFFFF); ld[3] = (int)(tot.y >> 16);
            ld[4] = (int)(tot.z & 0xFFFF); ld[5] = (int)(tot.z >> 16);
            ld[6] = (int)(tot.w & 0xFFFF); ld[7] = (int)(tot.w >> 16);
            int acc = 0;
#pragma unroll
            for (int e = 0; e < E_EXP; ++e) { u.s.loads[e] = ld[e]; u.s.base[e] = acc; acc += ld[e]; }
        }
        __syncthreads();
        if (tid < 256) {
            const int obase = tid * 8;
            u.s.offlds[obase + 0] = u.s.base[0] + (int)((v.x - own.x) & 0xFFFF);
            u.s.offlds[obase + 1] = u.s.base[1] + (int)((v.x - own.x) >> 16);
            u.s.offlds[obase + 2] = u.s.base[2] + (int)((v.y - own.y) & 0xFFFF);
            u.s.offlds[obase + 3] = u.s.base[3] + (int)((v.y - own.y) >> 16);
            u.s.offlds[obase + 4] = u.s.base[4] + (int)((v.z - own.z) & 0xFFFF);
            u.s.offlds[obase + 5] = u.s.base[5] + (int)((v.z - own.z) >> 16);
            u.s.offlds[obase + 6] = u.s.base[6] + (int)((v.w - own.w) & 0xFFFF);
            u.s.offlds[obase + 7] = u.s.base[7] + (int)((v.w - own.w) >> 16);
            const int t0 = tid * 16;
            for (int k = 0; k < 16; ++k) {
                const TokRec r = rl[k];
                const int tok = t0 + k;
                int d0 = u.s.offlds[obase + r.e0]++;
                u.s.src[d0] = (unsigned short)tok;
                u.s.gate[d0] = r.g0;
                int d1 = u.s.offlds[obase + r.e1]++;
                u.s.src[d1] = (unsigned short)tok;
                u.s.gate[d1] = r.g1;
            }
        }
        if (b == 0 && tid < E_EXP) { /* after barrier below, loads valid */ }
        __syncthreads();
        if (b == 0 && tid < E_EXP) out_loads[tid] = (float)u.s.loads[tid];
    }

    // ---- Phase 3: write 128 contiguous rows; 4 rows in flight (sub) ----
    {
        const int sub = tid >> 8;            // 0..3
        const int t256 = tid & 255;
        const int col = t256 * 8;
        const int row0 = b * ROWS_PER_BLK;
        const int e = row0 >> 12;            // all 128 rows share one expert
        const int le = u.s.loads[e];
        const int be = u.s.base[e];
#pragma unroll 4
        for (int k = 0; k < ROWS_PER_BLK / 4; ++k) {
            const int row = row0 + k * 4 + sub;
            const int r = row & (T_TOK - 1);
            float* orow = out_data + (size_t)row * D_DIM;
            if (r >= le) {
                if (t256 == 0) out_tags[row] = -1.0f;
                const f32x4 z = {0.f, 0.f, 0.f, 0.f};
                *reinterpret_cast<f32x4*>(orow + col) = z;
                *reinterpret_cast<f32x4*>(orow + col + 4) = z;
            } else {
                const int src = (int)u.s.src[be + r];
                const float g = u.s.gate[be + r];
                if (t256 == 0) out_tags[row] = (float)src;
                const float* xr = x + (size_t)src * D_DIM;
                f32x4 a = *reinterpret_cast<const f32x4*>(xr + col);
                f32x4 bb = *reinterpret_cast<const f32x4*>(xr + col + 4);
                a *= g;
                bb *= g;
                *reinterpret_cast<f32x4*>(orow + col) = a;
                *reinterpret_cast<f32x4*>(orow + col + 4) = bb;
            }
        }
    }
}

extern "C" void kernel_launch(void* const* d_in, const int* in_sizes, int n_in,
                              void* d_out, int out_size, void* d_ws, size_t ws_size,
                              hipStream_t stream) {
    const float* x  = (const float*)d_in[0];
    const float* Wg = (const float*)d_in[1];

    float* out       = (float*)d_out;
    float* out_data  = out;
    float* out_tags  = out + (size_t)E_EXP * T_TOK * D_DIM;
    float* out_loads = out_tags + E_EXP * T_TOK;

    char* ws = (char*)d_ws;
    TokRec*   recs = (TokRec*)ws;              // 64 KiB @ 0
    unsigned* bar  = (unsigned*)(ws + 65536);  // 4 B

    hipMemsetAsync(bar, 0, sizeof(unsigned), stream);
    fused_kernel<<<NBLK, BTHR, 0, stream>>>(x, Wg, recs, bar, out_data, out_tags, out_loads);
}

// Round 8
// 85.298 us; speedup vs baseline: 2.7125x; 2.7125x over previous
//
#include <hip/hip_runtime.h>
#include <math.h>

#define T_TOK 4096
#define D_DIM 2048
#define E_EXP 8

typedef float f32x4 __attribute__((ext_vector_type(4)));

struct TokRec { int e0, e1; float g0, g1; };

// ---------------- Kernel 1: per-block Wg->LDS transpose + gating ------------
// 1024 blocks x 256 threads (4 waves, 1 token per wave) — R5's validated
// gating geometry; Wg staged to LDS per block (R7's validated phase 0).
// fp64 accumulation, arithmetic order identical to R5 -> bit-identical routing.
__global__ __launch_bounds__(256) void gating_kernel(const float* __restrict__ x,
                                                     const float* __restrict__ Wg,
                                                     TokRec* __restrict__ recs) {
    __shared__ float wgt[E_EXP * D_DIM];   // 64 KB
    const int tid = threadIdx.x;

    // stage Wg[d][e] -> wgt[e][d] (coalesced global f32x4; 2-way LDS write conflicts = free)
#pragma unroll
    for (int it = 0; it < (E_EXP * D_DIM) / (256 * 4); ++it) {
        const int flat = (it * 256 + tid) * 4;
        const f32x4 w = *reinterpret_cast<const f32x4*>(Wg + flat);
        const int d = flat >> 3;
        const int e0 = flat & 7;           // 0 or 4
        wgt[(e0 + 0) * D_DIM + d] = w.x;
        wgt[(e0 + 1) * D_DIM + d] = w.y;
        wgt[(e0 + 2) * D_DIM + d] = w.z;
        wgt[(e0 + 3) * D_DIM + d] = w.w;
    }
    __syncthreads();

    const int wave = tid >> 6;
    const int lane = tid & 63;
    const int t = blockIdx.x * 4 + wave;
    const float* xr = x + (size_t)t * D_DIM;

    double acc[E_EXP];
#pragma unroll
    for (int e = 0; e < E_EXP; ++e) acc[e] = 0.0;
#pragma unroll
    for (int i = 0; i < D_DIM / 256; ++i) {
        const int d = i * 256 + lane * 4;
        const f32x4 xv = *reinterpret_cast<const f32x4*>(xr + d);
#pragma unroll
        for (int e = 0; e < E_EXP; ++e) {
            const f32x4 w = *reinterpret_cast<const f32x4*>(&wgt[e * D_DIM + d]);
            acc[e] += (double)xv.x * (double)w.x + (double)xv.y * (double)w.y
                    + (double)xv.z * (double)w.z + (double)xv.w * (double)w.w;
        }
    }
#pragma unroll
    for (int e = 0; e < E_EXP; ++e) {
        double v = acc[e];
#pragma unroll
        for (int off = 32; off > 0; off >>= 1) v += __shfl_xor(v, off, 64);
        acc[e] = v;
    }
    if (lane == 0) {
        double m = acc[0];
#pragma unroll
        for (int e = 1; e < E_EXP; ++e) m = (acc[e] > m) ? acc[e] : m;
        double Z = 0.0;
#pragma unroll
        for (int e = 0; e < E_EXP; ++e) Z += exp(acc[e] - m);
        int e0 = 0;
#pragma unroll
        for (int e = 1; e < E_EXP; ++e) if (acc[e] > acc[e0]) e0 = e;
        int e1 = (e0 == 0) ? 1 : 0;
#pragma unroll
        for (int e = 0; e < E_EXP; ++e) if (e != e0 && acc[e] > acc[e1]) e1 = e;
        TokRec r;
        r.e0 = e0; r.e1 = e1;
        r.g0 = (float)(exp(acc[e0] - m) / Z);
        r.g1 = (float)(exp(acc[e1] - m) / Z);
        recs[t] = r;
    }
}

// ---------------- Kernel 2: redundant per-block scan + scatter ---------------
// 512 blocks x 256 threads; each block rebuilds the full routing scan in LDS
// (deterministic, identical in every block — R6's validated phase 2), then
// writes its own 64 contiguous output rows + tags. No grid barrier, no global
// smap round-trip, no separate scan dispatch.
__global__ __launch_bounds__(256) void scan_scatter_kernel(const float* __restrict__ x,
                                                           const TokRec* __restrict__ recs,
                                                           float* __restrict__ out_data,
                                                           float* __restrict__ out_tags,
                                                           float* __restrict__ out_loads) {
    __shared__ uint4 sb[256];                  // 4 KB
    __shared__ int offlds[256 * 8];            // 8 KB
    __shared__ unsigned short ssrc[2 * T_TOK]; // 16 KB
    __shared__ float sgate[2 * T_TOK];         // 32 KB
    __shared__ int sloads[E_EXP];
    __shared__ int sbase[E_EXP];
    const int tid = threadIdx.x;

    // ---- scan (validated R5/R6 algorithm) ----
    const int t0 = tid * 16;
    unsigned long long c = 0ULL;
    TokRec rl[16];
    for (int k = 0; k < 16; ++k) {
        rl[k] = recs[t0 + k];
        c += 1ULL << (rl[k].e0 * 8);
        c += 1ULL << (rl[k].e1 * 8);
    }
    uint4 v;
    v.x = (unsigned)((c       ) & 0xFF) | ((unsigned)((c >>  8) & 0xFF) << 16);
    v.y = (unsigned)((c >> 16 ) & 0xFF) | ((unsigned)((c >> 24) & 0xFF) << 16);
    v.z = (unsigned)((c >> 32 ) & 0xFF) | ((unsigned)((c >> 40) & 0xFF) << 16);
    v.w = (unsigned)((c >> 48 ) & 0xFF) | ((unsigned)((c >> 56) & 0xFF) << 16);
    const uint4 own = v;
    sb[tid] = v;
    for (int d = 1; d < 256; d <<= 1) {
        __syncthreads();
        uint4 o = make_uint4(0u, 0u, 0u, 0u);
        if (tid >= d) o = sb[tid - d];
        __syncthreads();
        v.x += o.x; v.y += o.y; v.z += o.z; v.w += o.w;
        sb[tid] = v;
    }
    __syncthreads();
    if (tid == 0) {
        const uint4 tot = sb[255];
        int ld[8];
        ld[0] = (int)(tot.x & 0xFFFF); ld[1] = (int)(tot.x >> 16);
        ld[2] = (int)(tot.y & 0xFFFF); ld[3] = (int)(tot.y >> 16);
        ld[4] = (int)(tot.z & 0xFFFF); ld[5] = (int)(tot.z >> 16);
        ld[6] = (int)(tot.w & 0xFFFF); ld[7] = (int)(tot.w >> 16);
        int acc = 0;
#pragma unroll
        for (int e = 0; e < E_EXP; ++e) { sloads[e] = ld[e]; sbase[e] = acc; acc += ld[e]; }
    }
    __syncthreads();
    const int obase = tid * 8;
    offlds[obase + 0] = sbase[0] + (int)((v.x - own.x) & 0xFFFF);
    offlds[obase + 1] = sbase[1] + (int)((v.x - own.x) >> 16);
    offlds[obase + 2] = sbase[2] + (int)((v.y - own.y) & 0xFFFF);
    offlds[obase + 3] = sbase[3] + (int)((v.y - own.y) >> 16);
    offlds[obase + 4] = sbase[4] + (int)((v.z - own.z) & 0xFFFF);
    offlds[obase + 5] = sbase[5] + (int)((v.z - own.z) >> 16);
    offlds[obase + 6] = sbase[6] + (int)((v.w - own.w) & 0xFFFF);
    offlds[obase + 7] = sbase[7] + (int)((v.w - own.w) >> 16);
    for (int k = 0; k < 16; ++k) {
        const TokRec r = rl[k];
        const int tok = t0 + k;
        int d0 = offlds[obase + r.e0]++;
        ssrc[d0] = (unsigned short)tok;
        sgate[d0] = r.g0;
        int d1 = offlds[obase + r.e1]++;
        ssrc[d1] = (unsigned short)tok;
        sgate[d1] = r.g1;
    }
    __syncthreads();

    // ---- this block's 64 rows: [row0, row0+64), all within one expert ----
    const int row0 = blockIdx.x * 64;
    const int e = row0 >> 12;
    const int le = sloads[e];
    const int be = sbase[e];

    if (tid < 64) {
        const int r = (row0 + tid) & (T_TOK - 1);
        out_tags[row0 + tid] = (r < le) ? (float)ssrc[be + r] : -1.0f;
    }
    if (blockIdx.x == 0 && tid < E_EXP) out_loads[tid] = (float)sloads[tid];

    const int col = tid * 8;
#pragma unroll 4
    for (int k = 0; k < 64; ++k) {
        const int row = row0 + k;
        const int r = row & (T_TOK - 1);
        float* orow = out_data + (size_t)row * D_DIM;
        if (r >= le) {
            const f32x4 z = {0.f, 0.f, 0.f, 0.f};
            *reinterpret_cast<f32x4*>(orow + col) = z;
            *reinterpret_cast<f32x4*>(orow + col + 4) = z;
        } else {
            const int src = (int)ssrc[be + r];
            const float g = sgate[be + r];
            const float* xr = x + (size_t)src * D_DIM;
            f32x4 a = *reinterpret_cast<const f32x4*>(xr + col);
            f32x4 b = *reinterpret_cast<const f32x4*>(xr + col + 4);
            a *= g;
            b *= g;
            *reinterpret_cast<f32x4*>(orow + col) = a;
            *reinterpret_cast<f32x4*>(orow + col + 4) = b;
        }
    }
}

extern "C" void kernel_launch(void* const* d_in, const int* in_sizes, int n_in,
                              void* d_out, int out_size, void* d_ws, size_t ws_size,
                              hipStream_t stream) {
    const float* x  = (const float*)d_in[0];
    const float* Wg = (const float*)d_in[1];

    float* out       = (float*)d_out;
    float* out_data  = out;
    float* out_tags  = out + (size_t)E_EXP * T_TOK * D_DIM;
    float* out_loads = out_tags + E_EXP * T_TOK;

    TokRec* recs = (TokRec*)d_ws;              // 64 KiB

    gating_kernel<<<T_TOK / 4, 256, 0, stream>>>(x, Wg, recs);
    scan_scatter_kernel<<<(E_EXP * T_TOK) / 64, 256, 0, stream>>>(x, recs, out_data, out_tags, out_loads);
}